// Round 3
// baseline (239.277 us; speedup 1.0000x reference)
//
#include <hip/hip_runtime.h>
#include <math.h>

// Per-position head-vs-head attention (Hilbert perm cancels; see R0 notes).
// R2 redesign: NO LDS AT ALL. One wave per position, lane = (head i, 16-dim
// sub-chunk s). Every k/v read instruction has only 8 distinct addresses
// across the 64 lanes (2 groups x 4 chunks); the 8-way head redundancy is a
// same-address broadcast that the VMEM path dedups, so direct-global reads
// carry ZERO redundant traffic. This deletes the LDS staging latency chain
// (R1's bottleneck: all pipes <35%, occupancy LDS-capped at 36%) and lifts
// occupancy to the VGPR limit.

#define HEADS 16
#define DIM 64
#define WAVES_PER_BLOCK 4

__global__ void __launch_bounds__(256) hilbert_attn_kernel(
    const float* __restrict__ q,
    const float* __restrict__ k,
    const float* __restrict__ v,
    float* __restrict__ out,
    int npos)
{
    const int t    = threadIdx.x;
    const int wave = t >> 6;
    const int lane = t & 63;
    const long long pos = (long long)blockIdx.x * WAVES_PER_BLOCK + wave;
    if (pos >= npos) return;

    const long long gbase = pos * (HEADS * DIM);

    const int i   = lane >> 2;        // head 0..15
    const int s   = lane & 3;         // 16-float sub-chunk of dim
    const int grp = i >> 3;           // head group 0/1

    // ---- q sub-row: lane-private 16 floats (issued first, longest chain).
    const float* qp = q + gbase + i * DIM + s * 16;
    float4 q0 = *(const float4*)(qp + 0);
    float4 q1 = *(const float4*)(qp + 4);
    float4 q2 = *(const float4*)(qp + 8);
    float4 q3 = *(const float4*)(qp + 12);

    // ---- Phase A: partial scores over this lane's 16 dims, direct global k.
    // Each instr: 8 distinct 16B segments, 8-way lane broadcast -> no
    // redundant fetch; total phase-A traffic == k's 4KB exactly.
    const float* kg = k + gbase + grp * (8 * DIM) + s * 16;
    float sc[8];
    #pragma unroll
    for (int j = 0; j < 8; ++j) {
        const float* kr = kg + j * DIM;
        float4 k0 = *(const float4*)(kr + 0);
        float4 k1 = *(const float4*)(kr + 4);
        float4 k2 = *(const float4*)(kr + 8);
        float4 k3 = *(const float4*)(kr + 12);
        sc[j] = q0.x*k0.x + q0.y*k0.y + q0.z*k0.z + q0.w*k0.w
              + q1.x*k1.x + q1.y*k1.y + q1.z*k1.z + q1.w*k1.w
              + q2.x*k2.x + q2.y*k2.y + q2.z*k2.z + q2.w*k2.w
              + q3.x*k3.x + q3.y*k3.y + q3.z*k3.z + q3.w*k3.w;
    }
    // Complete dots across the 4 s-lanes (masks 1,2 = quad_perm DPP, cheap).
    #pragma unroll
    for (int j = 0; j < 8; ++j) {
        sc[j] += __shfl_xor(sc[j], 1);
        sc[j] += __shfl_xor(sc[j], 2);
        sc[j] *= 0.125f;              // HEAD_DIM^-0.5
    }

    // ---- Softmax fully in-lane (each s-lane holds the full score row).
    float m = sc[0];
    #pragma unroll
    for (int j = 1; j < 8; ++j) m = fmaxf(m, sc[j]);
    float sum = 0.f;
    float at[8];
    #pragma unroll
    for (int j = 0; j < 8; ++j) { at[j] = __expf(sc[j] - m); sum += at[j]; }
    const float inv = 1.f / sum;
    #pragma unroll
    for (int j = 0; j < 8; ++j) at[j] *= inv;

    // ---- Phase B: direct global v, same broadcast-dedup property.
    const float* vg = v + gbase + grp * (8 * DIM) + s * 16;
    float4 o0 = make_float4(0,0,0,0), o1 = o0, o2 = o0, o3 = o0;
    #pragma unroll
    for (int j = 0; j < 8; ++j) {
        const float a = at[j];
        const float* vr = vg + j * DIM;
        float4 v0 = *(const float4*)(vr + 0);
        float4 v1 = *(const float4*)(vr + 4);
        float4 v2 = *(const float4*)(vr + 8);
        float4 v3 = *(const float4*)(vr + 12);
        o0.x += a*v0.x; o0.y += a*v0.y; o0.z += a*v0.z; o0.w += a*v0.w;
        o1.x += a*v1.x; o1.y += a*v1.y; o1.z += a*v1.z; o1.w += a*v1.w;
        o2.x += a*v2.x; o2.y += a*v2.y; o2.z += a*v2.z; o2.w += a*v2.w;
        o3.x += a*v3.x; o3.y += a*v3.y; o3.z += a*v3.z; o3.w += a*v3.w;
    }

    // ---- Store: lane-private 64B; wave covers contiguous 4KB.
    float* op = out + gbase + i * DIM + s * 16;
    *(float4*)(op + 0)  = o0;
    *(float4*)(op + 4)  = o1;
    *(float4*)(op + 8)  = o2;
    *(float4*)(op + 12) = o3;
}

extern "C" void kernel_launch(void* const* d_in, const int* in_sizes, int n_in,
                              void* d_out, int out_size, void* d_ws, size_t ws_size,
                              hipStream_t stream) {
    const float* q = (const float*)d_in[0];
    const float* k = (const float*)d_in[1];
    const float* v = (const float*)d_in[2];
    float* out = (float*)d_out;

    const int npos = in_sizes[0] / (HEADS * DIM);   // B*S = 16384
    const int blocks = (npos + WAVES_PER_BLOCK - 1) / WAVES_PER_BLOCK;
    hilbert_attn_kernel<<<blocks, 256, 0, stream>>>(q, k, v, out, npos);
}

// Round 4
// 236.636 us; speedup vs baseline: 1.0112x; 1.0112x over previous
//
#include <hip/hip_runtime.h>
#include <math.h>

// Per-position head-vs-head attention (Hilbert perm cancels; see R0 notes).
// R3: R2 was latency-serialized -- VGPR_Count=36 meant ~2 loads in flight,
// ~30us wave lifetime (268MB/110us/256CU = 4 B/cyc/CU). Fix: explicit
// register-array batching. All 32 k-loads issued as one batch (descending
// vmcnt waits keep them in flight), all 32 v-loads batched into the reused
// registers before softmax. __launch_bounds__(256,2) budgets 256 VGPRs so
// the scheduler keeps the batch wide. 8 waves/CU x 32KB in flight >> 17KB
// Little's-law requirement.

#define HEADS 16
#define DIM 64
#define WAVES_PER_BLOCK 4

__global__ void __launch_bounds__(256, 2) hilbert_attn_kernel(
    const float* __restrict__ q,
    const float* __restrict__ k,
    const float* __restrict__ v,
    float* __restrict__ out,
    int npos)
{
    const int t    = threadIdx.x;
    const int wave = t >> 6;
    const int lane = t & 63;
    const long long pos = (long long)blockIdx.x * WAVES_PER_BLOCK + wave;
    if (pos >= npos) return;

    const long long gbase = pos * (HEADS * DIM);

    const int i   = lane >> 2;        // head 0..15
    const int s   = lane & 3;         // 16-float sub-chunk of dim
    const int grp = i >> 3;           // head group 0/1

    // ---- Batch 1: q sub-row (16 floats) + ALL k rows (32 float4 = 128 VGPR).
    const float* qp = q + gbase + i * DIM + s * 16;
    float4 q0 = *(const float4*)(qp + 0);
    float4 q1 = *(const float4*)(qp + 4);
    float4 q2 = *(const float4*)(qp + 8);
    float4 q3 = *(const float4*)(qp + 12);

    const float* kg = k + gbase + grp * (8 * DIM) + s * 16;
    float4 kr[8][4];
    #pragma unroll
    for (int j = 0; j < 8; ++j) {
        #pragma unroll
        for (int c = 0; c < 4; ++c)
            kr[j][c] = *(const float4*)(kg + j * DIM + c * 4);
    }

    // ---- Phase A: consume k rows in order (tail loads still in flight).
    float sc[8];
    #pragma unroll
    for (int j = 0; j < 8; ++j) {
        sc[j] = q0.x*kr[j][0].x + q0.y*kr[j][0].y + q0.z*kr[j][0].z + q0.w*kr[j][0].w
              + q1.x*kr[j][1].x + q1.y*kr[j][1].y + q1.z*kr[j][1].z + q1.w*kr[j][1].w
              + q2.x*kr[j][2].x + q2.y*kr[j][2].y + q2.z*kr[j][2].z + q2.w*kr[j][2].w
              + q3.x*kr[j][3].x + q3.y*kr[j][3].y + q3.z*kr[j][3].z + q3.w*kr[j][3].w;
    }

    // ---- Batch 2: ALL v rows (reuses the now-dead k registers). Issued
    // before softmax so the exp/recip chain hides the head of the latency.
    const float* vg = v + gbase + grp * (8 * DIM) + s * 16;
    float4 vr[8][4];
    #pragma unroll
    for (int j = 0; j < 8; ++j) {
        #pragma unroll
        for (int c = 0; c < 4; ++c)
            vr[j][c] = *(const float4*)(vg + j * DIM + c * 4);
    }

    // ---- Complete dots across the 4 s-lanes + softmax (fully in-lane).
    #pragma unroll
    for (int j = 0; j < 8; ++j) {
        sc[j] += __shfl_xor(sc[j], 1);
        sc[j] += __shfl_xor(sc[j], 2);
        sc[j] *= 0.125f;              // HEAD_DIM^-0.5
    }
    float m = sc[0];
    #pragma unroll
    for (int j = 1; j < 8; ++j) m = fmaxf(m, sc[j]);
    float sum = 0.f;
    float at[8];
    #pragma unroll
    for (int j = 0; j < 8; ++j) { at[j] = __expf(sc[j] - m); sum += at[j]; }
    const float inv = 1.f / sum;
    #pragma unroll
    for (int j = 0; j < 8; ++j) at[j] *= inv;

    // ---- Phase B: out[i][s-chunk] = sum_j at[j] * v[grp*8+j][s-chunk].
    float4 o0 = make_float4(0,0,0,0), o1 = o0, o2 = o0, o3 = o0;
    #pragma unroll
    for (int j = 0; j < 8; ++j) {
        const float a = at[j];
        o0.x += a*vr[j][0].x; o0.y += a*vr[j][0].y; o0.z += a*vr[j][0].z; o0.w += a*vr[j][0].w;
        o1.x += a*vr[j][1].x; o1.y += a*vr[j][1].y; o1.z += a*vr[j][1].z; o1.w += a*vr[j][1].w;
        o2.x += a*vr[j][2].x; o2.y += a*vr[j][2].y; o2.z += a*vr[j][2].z; o2.w += a*vr[j][2].w;
        o3.x += a*vr[j][3].x; o3.y += a*vr[j][3].y; o3.z += a*vr[j][3].z; o3.w += a*vr[j][3].w;
    }

    // ---- Store: lane-private 64B; wave covers contiguous 4KB.
    float* op = out + gbase + i * DIM + s * 16;
    *(float4*)(op + 0)  = o0;
    *(float4*)(op + 4)  = o1;
    *(float4*)(op + 8)  = o2;
    *(float4*)(op + 12) = o3;
}

extern "C" void kernel_launch(void* const* d_in, const int* in_sizes, int n_in,
                              void* d_out, int out_size, void* d_ws, size_t ws_size,
                              hipStream_t stream) {
    const float* q = (const float*)d_in[0];
    const float* k = (const float*)d_in[1];
    const float* v = (const float*)d_in[2];
    float* out = (float*)d_out;

    const int npos = in_sizes[0] / (HEADS * DIM);   // B*S = 16384
    const int blocks = (npos + WAVES_PER_BLOCK - 1) / WAVES_PER_BLOCK;
    hilbert_attn_kernel<<<blocks, 256, 0, stream>>>(q, k, v, out, npos);
}